// Round 3
// baseline (612.811 us; speedup 1.0000x reference)
//
#include <hip/hip_runtime.h>

// AVWGCN: out[b,n,o] = sum_k sum_i xg_k[b,n,i] * w[k,i,o] + bias[o]
//   xg0 = x, xg1 = S@x, xg2 = 2*S@(S@x) - x   (S = softmax(relu(adj@emb), rows))
// Algebra: never form T2 = 2S@S - I; fold the "2*" and "-x" into Wcat.
// GEMMs: bf16 MFMA 16x16x32, m97 128x128 tile + XOR-swizzled LDS (bank-conflict-free)
// + GROUP_M=8 block swizzle for per-XCD L2 A-strip reuse.

typedef __bf16 bf16;
typedef __bf16 bf16x8 __attribute__((ext_vector_type(8)));
typedef float f32x4 __attribute__((ext_vector_type(4)));

__device__ __forceinline__ void async_lds16(const void* g, void* l) {
  __builtin_amdgcn_global_load_lds((const __attribute__((address_space(1))) void*)g,
                                   (__attribute__((address_space(3))) void*)l, 16, 0, 0);
}

// ---- S[n][m] = softmax(relu(adj@emb)) rows, stored bf16. 8 rows per block. ----
__global__ __launch_bounds__(256) void supports_k(const float* __restrict__ adj,
                                                  const float* __restrict__ emb,
                                                  bf16* __restrict__ S) {
  __shared__ float sadj[8][16];
  __shared__ float sred[4];
  const int tid = threadIdx.x;
  const int n0 = blockIdx.x * 8;
  if (tid < 128) sadj[tid >> 4][tid & 15] = adj[n0 * 16 + tid];
  __syncthreads();
  for (int r = 0; r < 8; ++r) {
    float vals[16];
    float mx = 0.f;  // relu => max >= 0
    #pragma unroll
    for (int it = 0; it < 16; ++it) {
      const int j = it * 256 + tid;
      float v = 0.f;
      #pragma unroll
      for (int e = 0; e < 16; ++e) v = fmaf(sadj[r][e], emb[e * 4096 + j], v);
      v = fmaxf(v, 0.f);
      vals[it] = v;
      mx = fmaxf(mx, v);
    }
    #pragma unroll
    for (int off = 32; off > 0; off >>= 1) mx = fmaxf(mx, __shfl_xor(mx, off, 64));
    if ((tid & 63) == 0) sred[tid >> 6] = mx;
    __syncthreads();
    mx = fmaxf(fmaxf(sred[0], sred[1]), fmaxf(sred[2], sred[3]));
    float sum = 0.f;
    #pragma unroll
    for (int it = 0; it < 16; ++it) {
      float ev = __expf(vals[it] - mx);
      vals[it] = ev;
      sum += ev;
    }
    #pragma unroll
    for (int off = 32; off > 0; off >>= 1) sum += __shfl_xor(sum, off, 64);
    __syncthreads();  // all reads of sred (max) done before reuse
    if ((tid & 63) == 0) sred[tid >> 6] = sum;
    __syncthreads();
    const float inv = 1.f / (sred[0] + sred[1] + sred[2] + sred[3]);
    bf16* Srow = S + (n0 + r) * 4096;
    #pragma unroll
    for (int it = 0; it < 16; ++it) Srow[it * 256 + tid] = (bf16)(vals[it] * inv);
    __syncthreads();  // sred reused next r
  }
}

// ---- Xt[b*64+c][m] = bf16(x[b][m][c])  (64x64 fp32 tile via LDS) ----
__global__ __launch_bounds__(256) void xpose_x_k(const float* __restrict__ x, bf16* __restrict__ Xt) {
  __shared__ float tile[64][65];
  const int tid = threadIdx.x;
  const int mt = blockIdx.x, b = blockIdx.y;
  const float* src = x + (b * 4096 + mt * 64) * 64;
  #pragma unroll
  for (int it = 0; it < 16; ++it) {
    const int idx = it * 256 + tid;
    tile[idx >> 6][idx & 63] = src[idx];  // idx = m_local*64 + c, coalesced
  }
  __syncthreads();
  #pragma unroll
  for (int it = 0; it < 16; ++it) {
    const int idx = it * 256 + tid;
    const int rr = idx >> 6, cc = idx & 63;  // rr = c (out row), cc = m_local (out col)
    Xt[(b * 64 + rr) * 4096 + mt * 64 + cc] = (bf16)tile[cc][rr];
  }
}

// ---- bf16 4096x4096 transpose: outT[j][i] = in[i][j] ----
__global__ __launch_bounds__(256) void transpose_bf16_k(const bf16* __restrict__ in, bf16* __restrict__ outT) {
  __shared__ bf16 tile[64][65];
  const int tid = threadIdx.x;
  const int ti = blockIdx.x & 63, tj = blockIdx.x >> 6;
  #pragma unroll
  for (int it = 0; it < 16; ++it) {
    const int idx = it * 256 + tid;
    tile[idx >> 6][idx & 63] = in[(ti * 64 + (idx >> 6)) * 4096 + tj * 64 + (idx & 63)];
  }
  __syncthreads();
  #pragma unroll
  for (int it = 0; it < 16; ++it) {
    const int idx = it * 256 + tid;
    const int rr = idx >> 6, cc = idx & 63;
    outT[(tj * 64 + rr) * 4096 + ti * 64 + cc] = tile[cc][rr];
  }
}

// ---- C[n][bc] = A[n][:] . Bt[bc][:]  (4096^3, both operands K-contig row-major) ----
// 128x128 tile, BK=32, 4 waves (2x2), 4x4 MFMA frags/wave.
// LDS layout XOR-swizzled on the k-block (8-elem chunk) index so ds_read_b128 is
// 2-way-max per bank (free); global_load_lds dst stays lane-contiguous (m104 rule),
// we permute each thread's GLOBAL source chunk instead.
__global__ __launch_bounds__(256) void gemm_bt_k(const bf16* __restrict__ A, const bf16* __restrict__ Bt,
                                                 bf16* __restrict__ C) {
  __shared__ bf16 As[128 * 32];
  __shared__ bf16 Bs[128 * 32];
  const int tid = threadIdx.x;

  // GROUP_M=8 swizzle: blocks with equal gid%8 (same XCD) share one tm row-strip.
  const int gid = blockIdx.x;
  const int tm = (gid >> 8) * 8 + (gid & 7);
  const int tn = (gid & 255) >> 3;
  const int rowBase = tm * 128, colBase = tn * 128;

  // staging: thread t -> row r=t>>2 (and r+64); physical k-block = t&3, logical = phys ^ swz(r)
  const int r = tid >> 2;
  const int sz = (r & 3) ^ ((r >> 2) & 3);       // swz(r) == swz(r+64)
  const int kp = ((tid & 3) ^ sz) * 8;
  const bf16* gA = A + (rowBase + r) * 4096 + kp;
  const bf16* gB = Bt + (colBase + r) * 4096 + kp;

  const int lane = tid & 63, wv = tid >> 6;
  bf16* ldsA = As + wv * 512;  // 1024B per wave per pass, lane*16B contiguous
  bf16* ldsB = Bs + wv * 512;

  const int t16 = lane & 15, quad = lane >> 4;
  const int szr = (t16 & 3) ^ ((t16 >> 2) & 3);  // row swz for reads (wm/wn don't affect it)
  const int wm = (wv >> 1) * 64, wn = (wv & 1) * 64;
  const bf16* pA = As + (wm + t16) * 32 + ((quad ^ szr) << 3);
  const bf16* pB = Bs + (wn + t16) * 32 + ((quad ^ szr) << 3);

  f32x4 acc[4][4];
  #pragma unroll
  for (int i = 0; i < 4; ++i)
    #pragma unroll
    for (int j = 0; j < 4; ++j) acc[i][j] = (f32x4){0.f, 0.f, 0.f, 0.f};

  for (int k0 = 0; k0 < 4096; k0 += 32) {
    __syncthreads();  // prior-iter LDS reads complete
    async_lds16(gA + k0, ldsA);
    async_lds16(gA + 64 * 4096 + k0, ldsA + 2048);
    async_lds16(gB + k0, ldsB);
    async_lds16(gB + 64 * 4096 + k0, ldsB + 2048);
    __syncthreads();  // implies s_waitcnt vmcnt(0): staging visible
    bf16x8 af[4], bfv[4];
    #pragma unroll
    for (int i = 0; i < 4; ++i) af[i] = *(const bf16x8*)(pA + i * 16 * 32);
    #pragma unroll
    for (int j = 0; j < 4; ++j) bfv[j] = *(const bf16x8*)(pB + j * 16 * 32);
    #pragma unroll
    for (int i = 0; i < 4; ++i)
      #pragma unroll
      for (int j = 0; j < 4; ++j)
        acc[i][j] = __builtin_amdgcn_mfma_f32_16x16x32_bf16(af[i], bfv[j], acc[i][j], 0, 0, 0);
  }

  // D: row = quad*4+rr (M dim), col = t16 (N dim)
  #pragma unroll
  for (int i = 0; i < 4; ++i) {
    const int row0 = rowBase + wm + i * 16 + quad * 4;
    #pragma unroll
    for (int j = 0; j < 4; ++j) {
      const int col = colBase + wn + j * 16 + t16;
      #pragma unroll
      for (int rr = 0; rr < 4; ++rr)
        C[(row0 + rr) * 4096 + col] = (bf16)acc[i][j][rr];
    }
  }
}

// ---- mix: out[b][n][o] = sum_{kk<192} Acat[n][kk] * Wcat[o][kk] + bias[o]
//      Acat chunks: kk 0..63 from x (fp32, cvt), 64..127 from XG1, 128..191 from XG2
//      Wcat[o][kk] = [w0-w2 | w1 | 2*w2]^T computed in-block from w (no separate kernel).
__global__ __launch_bounds__(256) void mix_k(const float* __restrict__ x, const bf16* __restrict__ XG1,
                                             const bf16* __restrict__ XG2, const float* __restrict__ w,
                                             const float* __restrict__ bias, float* __restrict__ out) {
  __shared__ bf16 sW[64 * 200];  // stride 200: 16B-aligned rows, 2-way-max bank aliasing (free)
  const int tid = threadIdx.x;
  const int nt = blockIdx.x, b = blockIdx.y;
  // Build Wcat directly into LDS: 64*192 = 12288 elems, 48 per thread.
  #pragma unroll
  for (int v = 0; v < 48; ++v) {
    const int idx = v * 256 + tid;
    const int o = idx / 192, kk = idx - o * 192;
    const int k = kk >> 6, i = kk & 63;
    float val;
    if (k == 0)      val = w[i * 64 + o] - w[2 * 4096 + i * 64 + o];
    else if (k == 1) val = w[4096 + i * 64 + o];
    else             val = 2.f * w[2 * 4096 + i * 64 + o];
    sW[o * 200 + kk] = (bf16)val;
  }
  __syncthreads();

  const int lane = tid & 63, wv = tid >> 6;
  const int t16 = lane & 15, quad = lane >> 4;
  const int nBase = nt * 128 + wv * 32;

  f32x4 acc[2][4];
  #pragma unroll
  for (int i = 0; i < 2; ++i)
    #pragma unroll
    for (int j = 0; j < 4; ++j) acc[i][j] = (f32x4){0.f, 0.f, 0.f, 0.f};

  #pragma unroll
  for (int ch = 0; ch < 6; ++ch) {
    bf16x8 a[2];
    #pragma unroll
    for (int i = 0; i < 2; ++i) {
      const int row = nBase + i * 16 + t16;
      if (ch < 2) {
        const float* p = x + (b * 4096 + row) * 64 + ch * 32 + quad * 8;
        float4 f0 = *(const float4*)p;
        float4 f1 = *(const float4*)(p + 4);
        bf16x8 t;
        t[0] = (bf16)f0.x; t[1] = (bf16)f0.y; t[2] = (bf16)f0.z; t[3] = (bf16)f0.w;
        t[4] = (bf16)f1.x; t[5] = (bf16)f1.y; t[6] = (bf16)f1.z; t[7] = (bf16)f1.w;
        a[i] = t;
      } else {
        const bf16* src = (ch < 4) ? XG1 : XG2;
        a[i] = *(const bf16x8*)(src + row * 4096 + b * 64 + (ch & 1) * 32 + quad * 8);
      }
    }
    #pragma unroll
    for (int j = 0; j < 4; ++j) {
      bf16x8 wf = *(const bf16x8*)(sW + (j * 16 + t16) * 200 + ch * 32 + quad * 8);
      #pragma unroll
      for (int i = 0; i < 2; ++i)
        acc[i][j] = __builtin_amdgcn_mfma_f32_16x16x32_bf16(a[i], wf, acc[i][j], 0, 0, 0);
    }
  }

  #pragma unroll
  for (int j = 0; j < 4; ++j) {
    const float bb = bias[j * 16 + t16];
    #pragma unroll
    for (int i = 0; i < 2; ++i) {
      const int n0 = nBase + i * 16 + quad * 4;
      #pragma unroll
      for (int rr = 0; rr < 4; ++rr)
        out[(b * 4096 + n0 + rr) * 64 + j * 16 + t16] = acc[i][j][rr] + bb;
    }
  }
}

extern "C" void kernel_launch(void* const* d_in, const int* in_sizes, int n_in,
                              void* d_out, int out_size, void* d_ws, size_t ws_size,
                              hipStream_t stream) {
  const float* x    = (const float*)d_in[0];  // [64,4096,64]
  const float* adj  = (const float*)d_in[1];  // [4096,16]
  const float* emb  = (const float*)d_in[2];  // [16,4096]
  const float* w    = (const float*)d_in[3];  // [3,64,64]
  const float* bias = (const float*)d_in[4];  // [64]
  float* out = (float*)d_out;

  char* ws = (char*)d_ws;
  const size_t SZ = (size_t)4096 * 4096 * sizeof(bf16);  // 32 MiB
  bf16* S    = (bf16*)(ws);            // [n][m]
  bf16* XG1  = (bf16*)(ws + SZ);       // [n][bc]
  bf16* XG2  = (bf16*)(ws + 2 * SZ);   // [n][bc]
  bf16* XBUF = (bf16*)(ws + 3 * SZ);   // Xt [bc][m], later XG1t [bc][m]

  supports_k<<<512, 256, 0, stream>>>(adj, emb, S);
  xpose_x_k<<<dim3(64, 64), 256, 0, stream>>>(x, XBUF);
  gemm_bt_k<<<1024, 256, 0, stream>>>(S, XBUF, XG1);       // XG1 = S @ x
  transpose_bf16_k<<<4096, 256, 0, stream>>>(XG1, XBUF);   // XG1t
  gemm_bt_k<<<1024, 256, 0, stream>>>(S, XBUF, XG2);       // XG2 = S @ XG1
  mix_k<<<dim3(32, 64), 256, 0, stream>>>(x, XG1, XG2, w, bias, out);
}

// Round 4
// 471.092 us; speedup vs baseline: 1.3008x; 1.3008x over previous
//
#include <hip/hip_runtime.h>

// AVWGCN: out[b,n,o] = sum_k sum_i xg_k[b,n,i] * w[k,i,o] + bias[o]
//   xg0 = x, xg1 = S@x, xg2 = 2*S@(S@x) - x   (S = softmax(relu(adj@emb), rows))
// Algebra: never form T2; fold "2*" and "-x" into Wcat = [w0-w2 | w1 | 2*w2].
// GEMM: bf16 MFMA 16x16x32, 128x128 tile, BK=64 (halved barrier count vs m97's BK=32),
// XOR chunk-swizzle (required at BK=64: row stride 128B would be 16-way conflicted).

typedef __bf16 bf16;
typedef __bf16 bf16x8 __attribute__((ext_vector_type(8)));
typedef float f32x4 __attribute__((ext_vector_type(4)));

__device__ __forceinline__ void async_lds16(const void* g, void* l) {
  __builtin_amdgcn_global_load_lds((const __attribute__((address_space(1))) void*)g,
                                   (__attribute__((address_space(3))) void*)l, 16, 0, 0);
}

// ---- Wcat[o][kk] bf16, kk in [0,192): [w0-w2 | w1 | 2*w2] transposed to o-rows ----
__global__ __launch_bounds__(256) void build_wcat_k(const float* __restrict__ w, bf16* __restrict__ Wc) {
  int idx = blockIdx.x * 256 + threadIdx.x;
  if (idx >= 64 * 192) return;
  int o = idx / 192, kk = idx - o * 192;
  int k = kk >> 6, i = kk & 63;
  float v;
  if (k == 0)      v = w[i * 64 + o] - w[2 * 4096 + i * 64 + o];
  else if (k == 1) v = w[4096 + i * 64 + o];
  else             v = 2.f * w[2 * 4096 + i * 64 + o];
  Wc[idx] = (bf16)v;
}

// ---- S[n][m] = softmax(relu(adj@emb)) rows, stored bf16. 8 rows per block. ----
__global__ __launch_bounds__(256) void supports_k(const float* __restrict__ adj,
                                                  const float* __restrict__ emb,
                                                  bf16* __restrict__ S) {
  __shared__ float sadj[8][16];
  __shared__ float sred[4];
  const int tid = threadIdx.x;
  const int n0 = blockIdx.x * 8;
  if (tid < 128) sadj[tid >> 4][tid & 15] = adj[n0 * 16 + tid];
  __syncthreads();
  for (int r = 0; r < 8; ++r) {
    float vals[16];
    float mx = 0.f;  // relu => max >= 0
    #pragma unroll
    for (int it = 0; it < 16; ++it) {
      const int j = it * 256 + tid;
      float v = 0.f;
      #pragma unroll
      for (int e = 0; e < 16; ++e) v = fmaf(sadj[r][e], emb[e * 4096 + j], v);
      v = fmaxf(v, 0.f);
      vals[it] = v;
      mx = fmaxf(mx, v);
    }
    #pragma unroll
    for (int off = 32; off > 0; off >>= 1) mx = fmaxf(mx, __shfl_xor(mx, off, 64));
    if ((tid & 63) == 0) sred[tid >> 6] = mx;
    __syncthreads();
    mx = fmaxf(fmaxf(sred[0], sred[1]), fmaxf(sred[2], sred[3]));
    float sum = 0.f;
    #pragma unroll
    for (int it = 0; it < 16; ++it) {
      float ev = __expf(vals[it] - mx);
      vals[it] = ev;
      sum += ev;
    }
    #pragma unroll
    for (int off = 32; off > 0; off >>= 1) sum += __shfl_xor(sum, off, 64);
    __syncthreads();  // all reads of sred (max) done before reuse
    if ((tid & 63) == 0) sred[tid >> 6] = sum;
    __syncthreads();
    const float inv = 1.f / (sred[0] + sred[1] + sred[2] + sred[3]);
    bf16* Srow = S + (n0 + r) * 4096;
    #pragma unroll
    for (int it = 0; it < 16; ++it) Srow[it * 256 + tid] = (bf16)(vals[it] * inv);
    __syncthreads();  // sred reused next r
  }
}

// ---- Xt[b*64+c][m] = bf16(x[b][m][c])  (64x64 fp32 tile via LDS) ----
__global__ __launch_bounds__(256) void xpose_x_k(const float* __restrict__ x, bf16* __restrict__ Xt) {
  __shared__ float tile[64][65];
  const int tid = threadIdx.x;
  const int mt = blockIdx.x, b = blockIdx.y;
  const float* src = x + (b * 4096 + mt * 64) * 64;
  #pragma unroll
  for (int it = 0; it < 16; ++it) {
    const int idx = it * 256 + tid;
    tile[idx >> 6][idx & 63] = src[idx];  // idx = m_local*64 + c, coalesced
  }
  __syncthreads();
  #pragma unroll
  for (int it = 0; it < 16; ++it) {
    const int idx = it * 256 + tid;
    const int rr = idx >> 6, cc = idx & 63;  // rr = c (out row), cc = m_local (out col)
    Xt[(b * 64 + rr) * 4096 + mt * 64 + cc] = (bf16)tile[cc][rr];
  }
}

// ---- bf16 4096x4096 transpose: outT[j][i] = in[i][j] ----
__global__ __launch_bounds__(256) void transpose_bf16_k(const bf16* __restrict__ in, bf16* __restrict__ outT) {
  __shared__ bf16 tile[64][65];
  const int tid = threadIdx.x;
  const int ti = blockIdx.x & 63, tj = blockIdx.x >> 6;
  #pragma unroll
  for (int it = 0; it < 16; ++it) {
    const int idx = it * 256 + tid;
    tile[idx >> 6][idx & 63] = in[(ti * 64 + (idx >> 6)) * 4096 + tj * 64 + (idx & 63)];
  }
  __syncthreads();
  #pragma unroll
  for (int it = 0; it < 16; ++it) {
    const int idx = it * 256 + tid;
    const int rr = idx >> 6, cc = idx & 63;
    outT[(tj * 64 + rr) * 4096 + ti * 64 + cc] = tile[cc][rr];
  }
}

// ---- C[n][bc] = A[n][:] . Bt[bc][:]  (4096^3, both operands K-contig row-major) ----
// 128x128 tile, BK=64, 4 waves (2x2), 4x4 MFMA frags/wave, 2 k-subs per iter.
// LDS rows are 64 elems (128B): logical 8-elem chunk l of row r lives at phys l^(r&7).
// Writer permutes the GLOBAL source chunk (LDS dst must stay lane-linear, m104 rule);
// reader XORs the chunk index. Each 4-bank group then gets exactly 2 lanes (free, m136).
__global__ __launch_bounds__(256) void gemm_bt_k(const bf16* __restrict__ A, const bf16* __restrict__ Bt,
                                                 bf16* __restrict__ C) {
  __shared__ bf16 As[128 * 64];
  __shared__ bf16 Bs[128 * 64];
  const int tid = threadIdx.x;
  const int tm = blockIdx.x & 31, tn = blockIdx.x >> 5;
  const int rowBase = tm * 128, colBase = tn * 128;

  // staging: thread t -> row r=t>>3 (+32 per pass), phys chunk c=t&7 <- global chunk c^(r&7)
  const int r = tid >> 3;
  const int kp = ((tid & 7) ^ (r & 7)) * 8;
  const bf16* gA = A + (rowBase + r) * 4096 + kp;
  const bf16* gB = Bt + (colBase + r) * 4096 + kp;

  const int lane = tid & 63, wv = tid >> 6;
  bf16* ldsA = As + wv * 512;  // per-pass wave dst: 512 elems = 1KB, lane*16B contiguous
  bf16* ldsB = Bs + wv * 512;

  const int t16 = lane & 15, quad = lane >> 4;
  const int sz7 = t16 & 7;  // row-swizzle key; rows differ by multiples of 8 -> same key
  const int wm = (wv >> 1) * 64, wn = (wv & 1) * 64;
  const bf16* pA = As + (wm + t16) * 64;
  const bf16* pB = Bs + (wn + t16) * 64;

  f32x4 acc[4][4];
  #pragma unroll
  for (int i = 0; i < 4; ++i)
    #pragma unroll
    for (int j = 0; j < 4; ++j) acc[i][j] = (f32x4){0.f, 0.f, 0.f, 0.f};

  for (int k0 = 0; k0 < 4096; k0 += 64) {
    __syncthreads();  // prior-iter LDS reads complete
    #pragma unroll
    for (int p = 0; p < 4; ++p) {  // 4 passes x 32 rows = 128 rows per matrix
      async_lds16(gA + p * 32 * 4096 + k0, ldsA + p * 2048);
      async_lds16(gB + p * 32 * 4096 + k0, ldsB + p * 2048);
    }
    __syncthreads();  // implies s_waitcnt vmcnt(0): staging visible
    #pragma unroll
    for (int ks = 0; ks < 2; ++ks) {
      const int ch = ((ks * 4 + quad) ^ sz7) << 3;  // phys chunk offset, k-sub ks
      bf16x8 af[4], bfv[4];
      #pragma unroll
      for (int i = 0; i < 4; ++i) af[i] = *(const bf16x8*)(pA + i * 16 * 64 + ch);
      #pragma unroll
      for (int j = 0; j < 4; ++j) bfv[j] = *(const bf16x8*)(pB + j * 16 * 64 + ch);
      #pragma unroll
      for (int i = 0; i < 4; ++i)
        #pragma unroll
        for (int j = 0; j < 4; ++j)
          acc[i][j] = __builtin_amdgcn_mfma_f32_16x16x32_bf16(af[i], bfv[j], acc[i][j], 0, 0, 0);
    }
  }

  // D: row = quad*4+rr (M dim), col = t16 (N dim)
  #pragma unroll
  for (int i = 0; i < 4; ++i) {
    const int row0 = rowBase + wm + i * 16 + quad * 4;
    #pragma unroll
    for (int j = 0; j < 4; ++j) {
      const int col = colBase + wn + j * 16 + t16;
      #pragma unroll
      for (int rr = 0; rr < 4; ++rr)
        C[(row0 + rr) * 4096 + col] = (bf16)acc[i][j][rr];
    }
  }
}

// ---- mix: out[b][n][o] = sum_{kk<192} Acat[n][kk] * Wcat[o][kk] + bias[o]
//      Acat chunks: kk 0..63 from x (fp32, cvt), 64..127 from XG1, 128..191 from XG2
__global__ __launch_bounds__(256) void mix_k(const float* __restrict__ x, const bf16* __restrict__ XG1,
                                             const bf16* __restrict__ XG2, const bf16* __restrict__ Wc,
                                             const float* __restrict__ bias, float* __restrict__ out) {
  __shared__ bf16 sW[64 * 200];  // stride 200: 16B-aligned rows, 2-way-max bank aliasing (free)
  const int tid = threadIdx.x;
  const int nt = blockIdx.x, b = blockIdx.y;
  {
    // row = tid>>2 (64 rows), quarter = tid&3 covers 48 elems = 6 x bf16x8
    const int rw = tid >> 2, part = tid & 3;
    #pragma unroll
    for (int v = 0; v < 6; ++v)
      *(bf16x8*)(sW + rw * 200 + part * 48 + v * 8) = *(const bf16x8*)(Wc + rw * 192 + part * 48 + v * 8);
  }
  __syncthreads();

  const int lane = tid & 63, wv = tid >> 6;
  const int t16 = lane & 15, quad = lane >> 4;
  const int nBase = nt * 128 + wv * 32;

  f32x4 acc[2][4];
  #pragma unroll
  for (int i = 0; i < 2; ++i)
    #pragma unroll
    for (int j = 0; j < 4; ++j) acc[i][j] = (f32x4){0.f, 0.f, 0.f, 0.f};

  #pragma unroll
  for (int ch = 0; ch < 6; ++ch) {
    bf16x8 a[2];
    #pragma unroll
    for (int i = 0; i < 2; ++i) {
      const int row = nBase + i * 16 + t16;
      if (ch < 2) {
        const float* p = x + (b * 4096 + row) * 64 + ch * 32 + quad * 8;
        float4 f0 = *(const float4*)p;
        float4 f1 = *(const float4*)(p + 4);
        bf16x8 t;
        t[0] = (bf16)f0.x; t[1] = (bf16)f0.y; t[2] = (bf16)f0.z; t[3] = (bf16)f0.w;
        t[4] = (bf16)f1.x; t[5] = (bf16)f1.y; t[6] = (bf16)f1.z; t[7] = (bf16)f1.w;
        a[i] = t;
      } else {
        const bf16* src = (ch < 4) ? XG1 : XG2;
        a[i] = *(const bf16x8*)(src + row * 4096 + b * 64 + (ch & 1) * 32 + quad * 8);
      }
    }
    #pragma unroll
    for (int j = 0; j < 4; ++j) {
      bf16x8 wf = *(const bf16x8*)(sW + (j * 16 + t16) * 200 + ch * 32 + quad * 8);
      #pragma unroll
      for (int i = 0; i < 2; ++i)
        acc[i][j] = __builtin_amdgcn_mfma_f32_16x16x32_bf16(a[i], wf, acc[i][j], 0, 0, 0);
    }
  }

  #pragma unroll
  for (int j = 0; j < 4; ++j) {
    const float bb = bias[j * 16 + t16];
    #pragma unroll
    for (int i = 0; i < 2; ++i) {
      const int n0 = nBase + i * 16 + quad * 4;
      #pragma unroll
      for (int rr = 0; rr < 4; ++rr)
        out[(b * 4096 + n0 + rr) * 64 + j * 16 + t16] = acc[i][j][rr] + bb;
    }
  }
}

extern "C" void kernel_launch(void* const* d_in, const int* in_sizes, int n_in,
                              void* d_out, int out_size, void* d_ws, size_t ws_size,
                              hipStream_t stream) {
  const float* x    = (const float*)d_in[0];  // [64,4096,64]
  const float* adj  = (const float*)d_in[1];  // [4096,16]
  const float* emb  = (const float*)d_in[2];  // [16,4096]
  const float* w    = (const float*)d_in[3];  // [3,64,64]
  const float* bias = (const float*)d_in[4];  // [64]
  float* out = (float*)d_out;

  char* ws = (char*)d_ws;
  const size_t SZ = (size_t)4096 * 4096 * sizeof(bf16);  // 32 MiB
  bf16* S    = (bf16*)(ws);            // [n][m]
  bf16* XG1  = (bf16*)(ws + SZ);       // [n][bc]
  bf16* XG2  = (bf16*)(ws + 2 * SZ);   // [n][bc]
  bf16* XBUF = (bf16*)(ws + 3 * SZ);   // Xt [bc][m], later XG1t [bc][m]
  bf16* Wc   = (bf16*)(ws + 4 * SZ);   // [64][192]

  build_wcat_k<<<48, 256, 0, stream>>>(w, Wc);
  supports_k<<<512, 256, 0, stream>>>(adj, emb, S);
  xpose_x_k<<<dim3(64, 64), 256, 0, stream>>>(x, XBUF);
  gemm_bt_k<<<1024, 256, 0, stream>>>(S, XBUF, XG1);       // XG1 = S @ x
  transpose_bf16_k<<<4096, 256, 0, stream>>>(XG1, XBUF);   // XG1t
  gemm_bt_k<<<1024, 256, 0, stream>>>(S, XBUF, XG2);       // XG2 = S @ XG1
  mix_k<<<dim3(32, 64), 256, 0, stream>>>(x, XG1, XG2, Wc, bias, out);
}